// Round 9
// baseline (108.973 us; speedup 1.0000x reference)
//
#include <hip/hip_runtime.h>

#define NB 8
#define NN 2048
#define ND 128

typedef float f32x4 __attribute__((ext_vector_type(4)));
typedef __bf16 bf16x8 __attribute__((ext_vector_type(8)));
typedef unsigned short u16x4 __attribute__((ext_vector_type(4)));

__device__ __forceinline__ unsigned short f2bf(float f) {
  unsigned u = __builtin_bit_cast(unsigned, f);
  u = (u + 0x7FFFu + ((u >> 16) & 1u)) >> 16;
  return (unsigned short)u;
}

// async 16B global->LDS (DMA path); LDS dest = wave-uniform base + lane*16
__device__ __forceinline__ void stage16(const void* g, void* l) {
  __builtin_amdgcn_global_load_lds(
      (const __attribute__((address_space(1))) unsigned int*)g,
      (__attribute__((address_space(3))) unsigned int*)l, 16, 0, 0);
}

// K1: h = x @ W^T + b (fp32). hn = L2norm(h) bf16 [B*N, D]; hT = h bf16 [B, D, N].
__global__ __launch_bounds__(512, 2) void k_linear(
    const float* __restrict__ x, const float* __restrict__ W,
    const float* __restrict__ bias,
    unsigned short* __restrict__ hn, unsigned short* __restrict__ hT) {
  __shared__ __align__(16) float xs[128][68];
  __shared__ __align__(16) float wt[128][128];
  const int tid = threadIdx.x;
  const int rbase = blockIdx.x * 64;
  const int b = rbase >> 11;
  const int nb = rbase & (NN - 1);

#pragma unroll
  for (int j = 0; j < 4; ++j) {
    int f = tid + j * 512;
    int row = f >> 5;
    int kc = (f & 31) << 2;
    f32x4 v = *reinterpret_cast<const f32x4*>(&x[(size_t)(rbase + row) * ND + kc]);
#pragma unroll
    for (int i2 = 0; i2 < 4; ++i2) {
      int k = kc + i2;
      xs[k][row ^ (k & 28)] = v[i2];
    }
  }
#pragma unroll
  for (int j = 0; j < 8; ++j) {
    int f = tid + j * 512;
    int o = f >> 5;
    int i0 = (f & 31) << 2;
    f32x4 v = *reinterpret_cast<const f32x4*>(&W[(size_t)o * ND + i0]);
#pragma unroll
    for (int i2 = 0; i2 < 4; ++i2) {
      int k = i0 + i2;
      wt[k][o ^ (k & 28)] = v[i2];
    }
  }
  __syncthreads();

  const int tc = tid & 31;
  const int tr = tid >> 5;

  float acc[4][4];
#pragma unroll
  for (int r = 0; r < 4; ++r)
#pragma unroll
    for (int c = 0; c < 4; ++c) acc[r][c] = 0.f;

#pragma unroll 4
  for (int k = 0; k < 128; ++k) {
    const int sw = k & 28;
    f32x4 xv = *reinterpret_cast<const f32x4*>(&xs[k][(tr * 4) ^ sw]);
    f32x4 wv = *reinterpret_cast<const f32x4*>(&wt[k][(tc * 4) ^ sw]);
#pragma unroll
    for (int r = 0; r < 4; ++r)
#pragma unroll
      for (int c = 0; c < 4; ++c) acc[r][c] += xv[r] * wv[c];
  }

  f32x4 bv = *reinterpret_cast<const f32x4*>(&bias[tc * 4]);
#pragma unroll
  for (int r = 0; r < 4; ++r)
#pragma unroll
    for (int c = 0; c < 4; ++c) acc[r][c] += bv[c];

  float inv[4];
#pragma unroll
  for (int r = 0; r < 4; ++r) {
    float s = acc[r][0] * acc[r][0] + acc[r][1] * acc[r][1] +
              acc[r][2] * acc[r][2] + acc[r][3] * acc[r][3];
#pragma unroll
    for (int d = 1; d < 32; d <<= 1) s += __shfl_xor(s, d, 32);
    inv[r] = 1.f / fmaxf(sqrtf(s), 1e-12f);
  }

#pragma unroll
  for (int r = 0; r < 4; ++r) {
    u16x4 hv;
#pragma unroll
    for (int c = 0; c < 4; ++c) hv[c] = f2bf(acc[r][c] * inv[r]);
    *reinterpret_cast<u16x4*>(&hn[(size_t)(rbase + tr * 4 + r) * ND + tc * 4]) = hv;
  }
#pragma unroll
  for (int c = 0; c < 4; ++c) {
    u16x4 tv;
#pragma unroll
    for (int r = 0; r < 4; ++r) tv[r] = f2bf(acc[r][c]);
    *reinterpret_cast<u16x4*>(
        &hT[((size_t)b * ND + tc * 4 + c) * NN + nb + tr * 4]) = tv;
  }
}

// K2: part = (edge * (hn hn^T)) @ h over 512-key range. 512 blocks =
// (b=bid&7 [XCD], qt, kh), 8 waves, 2 blocks/CU. ONE barrier per tile
// (dbuf makes the second redundant); staging issued after the wait;
// kst-major read/MFMA clusters with setprio. Partials stored [row][kh][ND].
__global__ __launch_bounds__(512, 4) void k_fused(
    const float* __restrict__ edge,
    const unsigned short* __restrict__ hn,
    const unsigned short* __restrict__ hT,
    float* __restrict__ part) {
  __shared__ __align__(16) unsigned short Klds[2][64 * 128];
  __shared__ __align__(16) unsigned short Vlds[2][64 * 128];
  __shared__ __align__(16) unsigned short p_lds[8][16][64];

  const int tid = threadIdx.x;
  const int w = tid >> 6;
  const int l = tid & 63;
  const int m = l & 15;
  const int g = l >> 4;

  const int bid = blockIdx.x;
  const int b = bid & 7;
  const int qt = (bid >> 3) & 15;
  const int kh = bid >> 7;

  const int q0 = qt * 128 + w * 16;
  const unsigned short* hnb = hn + (size_t)b * NN * ND;
  const unsigned short* hTb = hT + (size_t)b * ND * NN;

  bf16x8 bq[4];
  {
    const unsigned short* qp = hnb + (size_t)(q0 + m) * ND + g * 8;
#pragma unroll
    for (int kst = 0; kst < 4; ++kst)
      bq[kst] = *reinterpret_cast<const bf16x8*>(qp + kst * 32);
  }

  f32x4 acc_o[8];
#pragma unroll
  for (int i = 0; i < 8; ++i) acc_o[i] = (f32x4){0.f, 0.f, 0.f, 0.f};

  const float* ep = edge + (size_t)b * NN * NN + (size_t)(q0 + m) * NN + kh * 512;

  // stage one 64-key tile; dest linear, source inverse-permuted (full 4-bit XOR)
  auto STAGE = [&](int kt, int buf) {
    const int kb = kh * 512 + kt * 64;
#pragma unroll
    for (int i = 0; i < 2; ++i) {
      int ch = tid + i * 512;
      int r = ch >> 4, c = ch & 15;
      int lg = c ^ (r & 15);
      stage16(hnb + (size_t)(kb + r) * ND + lg * 8,
              (char*)&Klds[buf][0] + (w * 64 + i * 512) * 16);
    }
#pragma unroll
    for (int i = 0; i < 2; ++i) {
      int ch = tid + i * 512;
      int fr = ch >> 4, c = ch & 15;
      int lg = c ^ (fr & 15);
      int ft = fr * 2 + (lg >> 3);
      stage16(hTb + (size_t)ft * NN + kb + (lg & 7) * 8,
              (char*)&Vlds[buf][0] + (w * 64 + i * 512) * 16);
    }
  };

  // one tile body; eg = this tile's edge regs, egn = next tile's (filled here)
  auto TILE = [&](int t, int A, f32x4* eg, f32x4* egn) {
    asm volatile("s_waitcnt vmcnt(0)" ::: "memory");  // tile t staged (issued 1 tile ago)
    __builtin_amdgcn_s_barrier();                     // all waves: buf A readable
    if (t < 7) {
      const float* epn = ep + (t + 1) * 64;
#pragma unroll
      for (int ct = 0; ct < 4; ++ct)
        egn[ct] = __builtin_nontemporal_load(
            reinterpret_cast<const f32x4*>(epn + ct * 16 + g * 4));
      STAGE(t + 1, A ^ 1);
    }

    const unsigned short* Ka = &Klds[A][0];
    const unsigned short* Va = &Vlds[A][0];

    // QK^T, kst-major clusters: 4 independent reads -> 4 independent MFMAs
    f32x4 st[4];
#pragma unroll
    for (int ct = 0; ct < 4; ++ct) st[ct] = (f32x4){0.f, 0.f, 0.f, 0.f};
#pragma unroll
    for (int kst = 0; kst < 4; ++kst) {
      bf16x8 ak[4];
#pragma unroll
      for (int ct = 0; ct < 4; ++ct) {
        const int r = ct * 16 + m;
        const int ph = (kst * 4 + g) ^ m;
        ak[ct] = *reinterpret_cast<const bf16x8*>(&Ka[r * 128 + ph * 8]);
      }
      __builtin_amdgcn_s_setprio(1);
#pragma unroll
      for (int ct = 0; ct < 4; ++ct)
        st[ct] = __builtin_amdgcn_mfma_f32_16x16x32_bf16(ak[ct], bq[kst], st[ct], 0, 0, 0);
      __builtin_amdgcn_s_setprio(0);
    }

    // gate + pack P[q=m][64 keys] (per-wave private, slot-XOR)
#pragma unroll
    for (int ct = 0; ct < 4; ++ct) {
      u16x4 pv;
#pragma unroll
      for (int r = 0; r < 4; ++r) pv[r] = f2bf(eg[ct][r] * st[ct][r]);
      const int ls = ct * 2 + (g >> 1);
      const int ps = ls ^ (m & 7);
      *reinterpret_cast<u16x4*>(&p_lds[w][m][ps * 8 + (g & 1) * 4]) = pv;
    }

    // PV, kst2-major clusters: 8 reads -> 8 independent MFMAs
#pragma unroll
    for (int kst2 = 0; kst2 < 2; ++kst2) {
      const int psa = (kst2 * 4 + g) ^ (m & 7);
      bf16x8 ap = *reinterpret_cast<const bf16x8*>(&p_lds[w][m][psa * 8]);
      bf16x8 bv[8];
#pragma unroll
      for (int ct2 = 0; ct2 < 8; ++ct2) {
        const int c2 = ct2 * 16 + m;
        const int fr = c2 >> 1;
        const int lg = (c2 & 1) * 8 + kst2 * 4 + g;
        const int ph = lg ^ (fr & 15);
        bv[ct2] = *reinterpret_cast<const bf16x8*>(&Va[fr * 128 + ph * 8]);
      }
      __builtin_amdgcn_s_setprio(1);
#pragma unroll
      for (int ct2 = 0; ct2 < 8; ++ct2)
        acc_o[ct2] = __builtin_amdgcn_mfma_f32_16x16x32_bf16(ap, bv[ct2], acc_o[ct2], 0, 0, 0);
      __builtin_amdgcn_s_setprio(0);
    }
  };

  // prologue: tile 0 staging + edge into egA
  STAGE(0, 0);
  f32x4 egA[4], egB[4];
#pragma unroll
  for (int ct = 0; ct < 4; ++ct)
    egA[ct] = __builtin_nontemporal_load(
        reinterpret_cast<const f32x4*>(ep + ct * 16 + g * 4));

#pragma unroll 1
  for (int t2 = 0; t2 < 4; ++t2) {  // tile pairs: static egA/egB ping-pong
    TILE(2 * t2, 0, egA, egB);
    TILE(2 * t2 + 1, 1, egB, egA);
  }

  // partial store, interleaved layout [row][kh][ND] (2 KB per-row clusters)
#pragma unroll
  for (int ct2 = 0; ct2 < 8; ++ct2)
#pragma unroll
    for (int r = 0; r < 4; ++r)
      part[((size_t)(b * NN + q0 + g * 4 + r) * 4 + kh) * ND + ct2 * 16 + m] =
          acc_o[ct2][r];
}

// merge 4 key-quarter partials + ReLU; XCD-affine block swizzle
__global__ __launch_bounds__(256) void k_merge(const float* __restrict__ part,
                                               float* __restrict__ out) {
  // 2048 blocks, 8 rows each; swizzle so block's rows' batch == its XCD
  const int bid = (int)blockIdx.x;
  const int nb = ((bid & 7) << 8) + (bid >> 3);  // bijective for grid 2048
  const int tid = threadIdx.x;
  const int row = nb * 8 + (tid >> 5);           // global row in [0, 8*2048)
  const int c4 = (tid & 31) * 4;
  const float* pr = part + ((size_t)row * 4) * ND + c4;
  f32x4 v = *reinterpret_cast<const f32x4*>(pr) +
            *reinterpret_cast<const f32x4*>(pr + ND) +
            *reinterpret_cast<const f32x4*>(pr + 2 * ND) +
            *reinterpret_cast<const f32x4*>(pr + 3 * ND);
#pragma unroll
  for (int j = 0; j < 4; ++j) v[j] = fmaxf(v[j], 0.f);
  *reinterpret_cast<f32x4*>(&out[(size_t)row * ND + c4]) = v;
}

extern "C" void kernel_launch(void* const* d_in, const int* in_sizes, int n_in,
                              void* d_out, int out_size, void* d_ws, size_t ws_size,
                              hipStream_t stream) {
  const float* x = (const float*)d_in[0];
  const float* edge = (const float*)d_in[1];
  const float* W = (const float*)d_in[2];
  const float* bias = (const float*)d_in[3];
  float* out = (float*)d_out;

  unsigned short* hn = (unsigned short*)d_ws;                  // 4 MB
  unsigned short* hT = hn + (size_t)NB * NN * ND;              // 4 MB
  float* part = (float*)((char*)d_ws + 2 * (size_t)NB * NN * ND * 2);  // 32 MB

  k_linear<<<dim3((NB * NN) / 64), dim3(512), 0, stream>>>(x, W, bias, hn, hT);
  k_fused<<<dim3(512), dim3(512), 0, stream>>>(edge, hn, hT, part);
  k_merge<<<dim3(2048), dim3(256), 0, stream>>>(part, out);
}

// Round 10
// 69.817 us; speedup vs baseline: 1.5608x; 1.5608x over previous
//
#include <hip/hip_runtime.h>

#define NB 8
#define NN 2048
#define ND 128

typedef float f32x4 __attribute__((ext_vector_type(4)));
typedef __bf16 bf16x8 __attribute__((ext_vector_type(8)));
typedef unsigned short u16x4 __attribute__((ext_vector_type(4)));

__device__ __forceinline__ unsigned short f2bf(float f) {
  unsigned u = __builtin_bit_cast(unsigned, f);
  u = (u + 0x7FFFu + ((u >> 16) & 1u)) >> 16;
  return (unsigned short)u;
}

// async 16B global->LDS (DMA path); LDS dest = wave-uniform base + lane*16
__device__ __forceinline__ void stage16(const void* g, void* l) {
  __builtin_amdgcn_global_load_lds(
      (const __attribute__((address_space(1))) unsigned int*)g,
      (__attribute__((address_space(3))) unsigned int*)l, 16, 0, 0);
}

// K1: h = x @ W^T + b (fp32). hn = L2norm(h) bf16 [B*N, D]; hT = h bf16 [B, D, N].
__global__ __launch_bounds__(512, 2) void k_linear(
    const float* __restrict__ x, const float* __restrict__ W,
    const float* __restrict__ bias,
    unsigned short* __restrict__ hn, unsigned short* __restrict__ hT) {
  __shared__ __align__(16) float xs[128][68];
  __shared__ __align__(16) float wt[128][128];
  const int tid = threadIdx.x;
  const int rbase = blockIdx.x * 64;
  const int b = rbase >> 11;
  const int nb = rbase & (NN - 1);

#pragma unroll
  for (int j = 0; j < 4; ++j) {
    int f = tid + j * 512;
    int row = f >> 5;
    int kc = (f & 31) << 2;
    f32x4 v = *reinterpret_cast<const f32x4*>(&x[(size_t)(rbase + row) * ND + kc]);
#pragma unroll
    for (int i2 = 0; i2 < 4; ++i2) {
      int k = kc + i2;
      xs[k][row ^ (k & 28)] = v[i2];
    }
  }
#pragma unroll
  for (int j = 0; j < 8; ++j) {
    int f = tid + j * 512;
    int o = f >> 5;
    int i0 = (f & 31) << 2;
    f32x4 v = *reinterpret_cast<const f32x4*>(&W[(size_t)o * ND + i0]);
#pragma unroll
    for (int i2 = 0; i2 < 4; ++i2) {
      int k = i0 + i2;
      wt[k][o ^ (k & 28)] = v[i2];
    }
  }
  __syncthreads();

  const int tc = tid & 31;
  const int tr = tid >> 5;

  float acc[4][4];
#pragma unroll
  for (int r = 0; r < 4; ++r)
#pragma unroll
    for (int c = 0; c < 4; ++c) acc[r][c] = 0.f;

#pragma unroll 4
  for (int k = 0; k < 128; ++k) {
    const int sw = k & 28;
    f32x4 xv = *reinterpret_cast<const f32x4*>(&xs[k][(tr * 4) ^ sw]);
    f32x4 wv = *reinterpret_cast<const f32x4*>(&wt[k][(tc * 4) ^ sw]);
#pragma unroll
    for (int r = 0; r < 4; ++r)
#pragma unroll
      for (int c = 0; c < 4; ++c) acc[r][c] += xv[r] * wv[c];
  }

  f32x4 bv = *reinterpret_cast<const f32x4*>(&bias[tc * 4]);
#pragma unroll
  for (int r = 0; r < 4; ++r)
#pragma unroll
    for (int c = 0; c < 4; ++c) acc[r][c] += bv[c];

  float inv[4];
#pragma unroll
  for (int r = 0; r < 4; ++r) {
    float s = acc[r][0] * acc[r][0] + acc[r][1] * acc[r][1] +
              acc[r][2] * acc[r][2] + acc[r][3] * acc[r][3];
#pragma unroll
    for (int d = 1; d < 32; d <<= 1) s += __shfl_xor(s, d, 32);
    inv[r] = 1.f / fmaxf(sqrtf(s), 1e-12f);
  }

#pragma unroll
  for (int r = 0; r < 4; ++r) {
    u16x4 hv;
#pragma unroll
    for (int c = 0; c < 4; ++c) hv[c] = f2bf(acc[r][c] * inv[r]);
    *reinterpret_cast<u16x4*>(&hn[(size_t)(rbase + tr * 4 + r) * ND + tc * 4]) = hv;
  }
#pragma unroll
  for (int c = 0; c < 4; ++c) {
    u16x4 tv;
#pragma unroll
    for (int r = 0; r < 4; ++r) tv[r] = f2bf(acc[r][c]);
    *reinterpret_cast<u16x4*>(
        &hT[((size_t)b * ND + tc * 4 + c) * NN + nb + tr * 4]) = tv;
  }
}

// K2: part[kh] = (edge * (hn hn^T)) @ h over a 512-key slice, 256 q-rows/block.
// 256 blocks = (b = bid&7 [XCD], qt = 0..7, kh = 0..3), 8 waves; each wave owns
// two 16-row fragments (f = 0,1 at +128 rows) -> every staged K/V byte and every
// ak/bv ds_read serves TWO fragments (staging bytes and LDS reads per MFMA
// halved vs the 128-row version). R7 two-barrier counted-vmcnt schedule.
__global__ __launch_bounds__(512) void k_fused(
    const float* __restrict__ edge,
    const unsigned short* __restrict__ hn,
    const unsigned short* __restrict__ hT,
    float* __restrict__ part) {
  __shared__ __align__(16) unsigned short Klds[2][64 * 128];   // 32 KB
  __shared__ __align__(16) unsigned short Vlds[2][64 * 128];   // 32 KB
  __shared__ __align__(16) unsigned short p_lds[8][2][16][64]; // 32 KB

  const int tid = threadIdx.x;
  const int w = tid >> 6;
  const int l = tid & 63;
  const int m = l & 15;
  const int g = l >> 4;

  const int bid = blockIdx.x;
  const int b = bid & 7;          // XCD-batch affinity
  const int qt = (bid >> 3) & 7;  // 256-row q tile
  const int kh = bid >> 6;        // 0..3 key quarter

  const int q0 = qt * 256 + w * 16;  // frag f adds f*128
  const unsigned short* hnb = hn + (size_t)b * NN * ND;
  const unsigned short* hTb = hT + (size_t)b * ND * NN;

  // Q fragments for both row-fragments
  bf16x8 bq[2][4];
#pragma unroll
  for (int f = 0; f < 2; ++f) {
    const unsigned short* qp = hnb + (size_t)(q0 + f * 128 + m) * ND + g * 8;
#pragma unroll
    for (int kst = 0; kst < 4; ++kst)
      bq[f][kst] = *reinterpret_cast<const bf16x8*>(qp + kst * 32);
  }

  f32x4 acc_o[2][8];
#pragma unroll
  for (int f = 0; f < 2; ++f)
#pragma unroll
    for (int i = 0; i < 8; ++i) acc_o[f][i] = (f32x4){0.f, 0.f, 0.f, 0.f};

  const float* ep[2];
  ep[0] = edge + (size_t)b * NN * NN + (size_t)(q0 + m) * NN + kh * 512;
  ep[1] = ep[0] + (size_t)128 * NN;

  // stage one 64-key tile; dest linear, source inverse-permuted (4-bit XOR)
  auto STAGE = [&](int kt, int buf) {
    const int kb = kh * 512 + kt * 64;
#pragma unroll
    for (int i = 0; i < 2; ++i) {
      int ch = tid + i * 512;
      int r = ch >> 4, c = ch & 15;
      int lg = c ^ (r & 15);
      stage16(hnb + (size_t)(kb + r) * ND + lg * 8,
              (char*)&Klds[buf][0] + (w * 64 + i * 512) * 16);
    }
#pragma unroll
    for (int i = 0; i < 2; ++i) {
      int ch = tid + i * 512;
      int fr = ch >> 4, c = ch & 15;
      int lg = c ^ (fr & 15);
      int ft = fr * 2 + (lg >> 3);
      stage16(hTb + (size_t)ft * NN + kb + (lg & 7) * 8,
              (char*)&Vlds[buf][0] + (w * 64 + i * 512) * 16);
    }
  };

  // one tile; eg/egn are [f*4+ct] register sets, static ping-pong outside
  auto TILE = [&](int t, int A, f32x4* eg, f32x4* egn) {
    if (t < 7) {
#pragma unroll
      for (int f = 0; f < 2; ++f) {
        const float* epn = ep[f] + (t + 1) * 64;
#pragma unroll
        for (int ct = 0; ct < 4; ++ct)
          egn[f * 4 + ct] = __builtin_nontemporal_load(
              reinterpret_cast<const f32x4*>(epn + ct * 16 + g * 4));
      }
      STAGE(t + 1, A ^ 1);
      // keep the 12 newest (next tile: 8 edge + 4 stage); tile t has landed
      asm volatile("s_waitcnt vmcnt(12)" ::: "memory");
    } else {
      asm volatile("s_waitcnt vmcnt(0)" ::: "memory");
    }
    __builtin_amdgcn_s_barrier();  // buf A readable by all waves

    const unsigned short* Ka = &Klds[A][0];
    const unsigned short* Va = &Vlds[A][0];

    // QK^T: ak fragments shared across both f
    f32x4 st[2][4];
#pragma unroll
    for (int f = 0; f < 2; ++f)
#pragma unroll
      for (int ct = 0; ct < 4; ++ct) st[f][ct] = (f32x4){0.f, 0.f, 0.f, 0.f};
#pragma unroll
    for (int kst = 0; kst < 4; ++kst) {
      bf16x8 ak[4];
#pragma unroll
      for (int ct = 0; ct < 4; ++ct) {
        const int r = ct * 16 + m;
        const int ph = (kst * 4 + g) ^ m;
        ak[ct] = *reinterpret_cast<const bf16x8*>(&Ka[r * 128 + ph * 8]);
      }
#pragma unroll
      for (int f = 0; f < 2; ++f)
#pragma unroll
        for (int ct = 0; ct < 4; ++ct)
          st[f][ct] = __builtin_amdgcn_mfma_f32_16x16x32_bf16(ak[ct], bq[f][kst],
                                                              st[f][ct], 0, 0, 0);
    }

    // gate + pack P[q=m][64 keys] per (wave, f)
#pragma unroll
    for (int f = 0; f < 2; ++f)
#pragma unroll
      for (int ct = 0; ct < 4; ++ct) {
        u16x4 pv;
#pragma unroll
        for (int r = 0; r < 4; ++r) pv[r] = f2bf(eg[f * 4 + ct][r] * st[f][ct][r]);
        const int ls = ct * 2 + (g >> 1);
        const int ps = ls ^ (m & 7);
        *reinterpret_cast<u16x4*>(&p_lds[w][f][m][ps * 8 + (g & 1) * 4]) = pv;
      }

    // PV: bv fragments shared across both f
#pragma unroll
    for (int kst2 = 0; kst2 < 2; ++kst2) {
      bf16x8 bv[8];
#pragma unroll
      for (int ct2 = 0; ct2 < 8; ++ct2) {
        const int c2 = ct2 * 16 + m;
        const int fr = c2 >> 1;
        const int lg = (c2 & 1) * 8 + kst2 * 4 + g;
        const int ph = lg ^ (fr & 15);
        bv[ct2] = *reinterpret_cast<const bf16x8*>(&Va[fr * 128 + ph * 8]);
      }
      const int psa = (kst2 * 4 + g) ^ (m & 7);
#pragma unroll
      for (int f = 0; f < 2; ++f) {
        bf16x8 ap = *reinterpret_cast<const bf16x8*>(&p_lds[w][f][m][psa * 8]);
#pragma unroll
        for (int ct2 = 0; ct2 < 8; ++ct2)
          acc_o[f][ct2] = __builtin_amdgcn_mfma_f32_16x16x32_bf16(ap, bv[ct2],
                                                                  acc_o[f][ct2], 0, 0, 0);
      }
    }

    // protect buffer A: next iteration stages tile t+2 into it
    __builtin_amdgcn_s_barrier();
  };

  // prologue: tile 0 + edge tile 0
  STAGE(0, 0);
  f32x4 egA[8], egB[8];
#pragma unroll
  for (int f = 0; f < 2; ++f)
#pragma unroll
    for (int ct = 0; ct < 4; ++ct)
      egA[f * 4 + ct] = __builtin_nontemporal_load(
          reinterpret_cast<const f32x4*>(ep[f] + ct * 16 + g * 4));

#pragma unroll 1
  for (int t2 = 0; t2 < 4; ++t2) {
    TILE(2 * t2, 0, egA, egB);
    TILE(2 * t2 + 1, 1, egB, egA);
  }

  // linear partial layout [kh][b*NN+row][ND] (R7-verified; no write-amp)
  float* pb = part + (size_t)kh * (NB * NN * ND);
#pragma unroll
  for (int f = 0; f < 2; ++f) {
    float* pf = pb + ((size_t)b * NN + q0 + f * 128) * ND;
#pragma unroll
    for (int ct2 = 0; ct2 < 8; ++ct2)
#pragma unroll
      for (int r = 0; r < 4; ++r)
        pf[(size_t)(g * 4 + r) * ND + ct2 * 16 + m] = acc_o[f][ct2][r];
  }
}

// merge 4 key-quarter partials + ReLU (R7-verified)
__global__ __launch_bounds__(256) void k_merge(const float* __restrict__ part,
                                               float* __restrict__ out, int n4) {
  int i = blockIdx.x * 256 + threadIdx.x;
  if (i >= n4) return;
  const f32x4* p = reinterpret_cast<const f32x4*>(part);
  const size_t s = (size_t)NB * NN * ND / 4;
  f32x4 v = p[i] + p[i + s] + p[i + 2 * s] + p[i + 3 * s];
#pragma unroll
  for (int j = 0; j < 4; ++j) v[j] = fmaxf(v[j], 0.f);
  reinterpret_cast<f32x4*>(out)[i] = v;
}

extern "C" void kernel_launch(void* const* d_in, const int* in_sizes, int n_in,
                              void* d_out, int out_size, void* d_ws, size_t ws_size,
                              hipStream_t stream) {
  const float* x = (const float*)d_in[0];
  const float* edge = (const float*)d_in[1];
  const float* W = (const float*)d_in[2];
  const float* bias = (const float*)d_in[3];
  float* out = (float*)d_out;

  unsigned short* hn = (unsigned short*)d_ws;                  // 4 MB
  unsigned short* hT = hn + (size_t)NB * NN * ND;              // 4 MB
  float* part = (float*)((char*)d_ws + 2 * (size_t)NB * NN * ND * 2);  // 32 MB

  k_linear<<<dim3((NB * NN) / 64), dim3(512), 0, stream>>>(x, W, bias, hn, hT);
  k_fused<<<dim3(256), dim3(512), 0, stream>>>(edge, hn, hT, part);
  const int n4 = out_size / 4;
  k_merge<<<dim3((n4 + 255) / 256), dim3(256), 0, stream>>>(part, out, n4);
}

// Round 11
// 57.758 us; speedup vs baseline: 1.8867x; 1.2088x over previous
//
#include <hip/hip_runtime.h>

#define NB 8
#define NN 2048
#define ND 128

typedef float f32x4 __attribute__((ext_vector_type(4)));
typedef __bf16 bf16x8 __attribute__((ext_vector_type(8)));
typedef unsigned short u16x4 __attribute__((ext_vector_type(4)));

__device__ __forceinline__ unsigned short f2bf(float f) {
  unsigned u = __builtin_bit_cast(unsigned, f);
  u = (u + 0x7FFFu + ((u >> 16) & 1u)) >> 16;
  return (unsigned short)u;
}

// async 16B global->LDS (DMA path); LDS dest = wave-uniform base + lane*16
__device__ __forceinline__ void stage16(const void* g, void* l) {
  __builtin_amdgcn_global_load_lds(
      (const __attribute__((address_space(1))) unsigned int*)g,
      (__attribute__((address_space(3))) unsigned int*)l, 16, 0, 0);
}

// K1: h = x @ W^T + b (fp32). hn = L2norm(h) bf16 [B*N, D]; hT = h bf16 [B, D, N].
__global__ __launch_bounds__(512, 2) void k_linear(
    const float* __restrict__ x, const float* __restrict__ W,
    const float* __restrict__ bias,
    unsigned short* __restrict__ hn, unsigned short* __restrict__ hT) {
  __shared__ __align__(16) float xs[128][68];
  __shared__ __align__(16) float wt[128][128];
  const int tid = threadIdx.x;
  const int rbase = blockIdx.x * 64;
  const int b = rbase >> 11;
  const int nb = rbase & (NN - 1);

#pragma unroll
  for (int j = 0; j < 4; ++j) {
    int f = tid + j * 512;
    int row = f >> 5;
    int kc = (f & 31) << 2;
    f32x4 v = *reinterpret_cast<const f32x4*>(&x[(size_t)(rbase + row) * ND + kc]);
#pragma unroll
    for (int i2 = 0; i2 < 4; ++i2) {
      int k = kc + i2;
      xs[k][row ^ (k & 28)] = v[i2];
    }
  }
#pragma unroll
  for (int j = 0; j < 8; ++j) {
    int f = tid + j * 512;
    int o = f >> 5;
    int i0 = (f & 31) << 2;
    f32x4 v = *reinterpret_cast<const f32x4*>(&W[(size_t)o * ND + i0]);
#pragma unroll
    for (int i2 = 0; i2 < 4; ++i2) {
      int k = i0 + i2;
      wt[k][o ^ (k & 28)] = v[i2];
    }
  }
  __syncthreads();

  const int tc = tid & 31;
  const int tr = tid >> 5;

  float acc[4][4];
#pragma unroll
  for (int r = 0; r < 4; ++r)
#pragma unroll
    for (int c = 0; c < 4; ++c) acc[r][c] = 0.f;

#pragma unroll 4
  for (int k = 0; k < 128; ++k) {
    const int sw = k & 28;
    f32x4 xv = *reinterpret_cast<const f32x4*>(&xs[k][(tr * 4) ^ sw]);
    f32x4 wv = *reinterpret_cast<const f32x4*>(&wt[k][(tc * 4) ^ sw]);
#pragma unroll
    for (int r = 0; r < 4; ++r)
#pragma unroll
      for (int c = 0; c < 4; ++c) acc[r][c] += xv[r] * wv[c];
  }

  f32x4 bv = *reinterpret_cast<const f32x4*>(&bias[tc * 4]);
#pragma unroll
  for (int r = 0; r < 4; ++r)
#pragma unroll
    for (int c = 0; c < 4; ++c) acc[r][c] += bv[c];

  float inv[4];
#pragma unroll
  for (int r = 0; r < 4; ++r) {
    float s = acc[r][0] * acc[r][0] + acc[r][1] * acc[r][1] +
              acc[r][2] * acc[r][2] + acc[r][3] * acc[r][3];
#pragma unroll
    for (int d = 1; d < 32; d <<= 1) s += __shfl_xor(s, d, 32);
    inv[r] = 1.f / fmaxf(sqrtf(s), 1e-12f);
  }

#pragma unroll
  for (int r = 0; r < 4; ++r) {
    u16x4 hv;
#pragma unroll
    for (int c = 0; c < 4; ++c) hv[c] = f2bf(acc[r][c] * inv[r]);
    *reinterpret_cast<u16x4*>(&hn[(size_t)(rbase + tr * 4 + r) * ND + tc * 4]) = hv;
  }
#pragma unroll
  for (int c = 0; c < 4; ++c) {
    u16x4 tv;
#pragma unroll
    for (int r = 0; r < 4; ++r) tv[r] = f2bf(acc[r][c]);
    *reinterpret_cast<u16x4*>(
        &hT[((size_t)b * ND + tc * 4 + c) * NN + nb + tr * 4]) = tv;
  }
}

// K2: part[kh] = (edge * (hn hn^T)) @ h over a 512-key slice, 256 q-rows/block.
// 256 blocks = (b = bid&7 [XCD], qt = 0..7, kh = 0..3), 8 waves, 16 tiles of
// 32 keys. ALL global streams (K, V, AND edge) staged via global_load_lds with
// involutive XOR slot swizzles; counted vmcnt(6) + two raw barriers per tile.
// LDS 112 KB -> 1 block/CU.
__global__ __launch_bounds__(512) void k_fused(
    const float* __restrict__ edge,
    const unsigned short* __restrict__ hn,
    const unsigned short* __restrict__ hT,
    float* __restrict__ part) {
  __shared__ __align__(16) unsigned short Klds[2][32 * 128];   // 2 x 8 KB
  __shared__ __align__(16) unsigned short Vlds[2][32 * 128];   // 2 x 8 KB
  __shared__ __align__(16) float Elds[2][256 * 32];            // 2 x 32 KB
  __shared__ __align__(16) unsigned short p_lds[8][2][16][32]; // 16 KB

  const int tid = threadIdx.x;
  const int w = tid >> 6;
  const int l = tid & 63;
  const int m = l & 15;
  const int g = l >> 4;

  const int bid = blockIdx.x;
  const int b = bid & 7;          // XCD-batch affinity
  const int qt = (bid >> 3) & 7;  // 256-row q tile
  const int kh = bid >> 6;        // 0..3 key quarter

  const int q00 = qt * 256;
  const int q0 = q00 + w * 16;    // frag f adds f*128
  const unsigned short* hnb = hn + (size_t)b * NN * ND;
  const unsigned short* hTb = hT + (size_t)b * ND * NN;
  const float* eb = edge + (size_t)b * NN * NN;

  // Q fragments for both row-fragments
  bf16x8 bq[2][4];
#pragma unroll
  for (int f = 0; f < 2; ++f) {
    const unsigned short* qp = hnb + (size_t)(q0 + f * 128 + m) * ND + g * 8;
#pragma unroll
    for (int kst = 0; kst < 4; ++kst)
      bq[f][kst] = *reinterpret_cast<const bf16x8*>(qp + kst * 32);
  }

  f32x4 acc_o[2][8];
#pragma unroll
  for (int f = 0; f < 2; ++f)
#pragma unroll
    for (int i = 0; i < 8; ++i) acc_o[f][i] = (f32x4){0.f, 0.f, 0.f, 0.f};

  // stage one 32-key tile: 6 stage16 per thread (K 1, V 1, E 4)
  auto STAGE = [&](int kt, int buf) {
    const int kb = kh * 512 + kt * 32;
    {  // K: 32 rows x 16 slots; phys c = lg ^ (r&15)
      int r = tid >> 4, c = tid & 15;
      int lg = c ^ (r & 15);
      stage16(hnb + (size_t)(kb + r) * ND + lg * 8,
              (char*)&Klds[buf][0] + (size_t)(w * 64) * 16);
    }
    {  // V: 32 rows (feature quads) x 16 slots; ft = fr*4 + (lg>>2), keys (lg&3)*8
      int fr = tid >> 4, c = tid & 15;
      int lg = c ^ (fr & 15);
      int ft = fr * 4 + (lg >> 2);
      stage16(hTb + (size_t)ft * NN + kb + (lg & 3) * 8,
              (char*)&Vlds[buf][0] + (size_t)(w * 64) * 16);
    }
#pragma unroll
    for (int i = 0; i < 4; ++i) {  // E: 256 rows x 8 slots; phys c = lg ^ (r&7)
      int ch = tid + i * 512;
      int r2 = ch >> 3, c = ch & 7;
      int lg = c ^ (r2 & 7);
      stage16(eb + (size_t)(q00 + r2) * NN + kb + lg * 4,
              (char*)&Elds[buf][0] + (size_t)(w * 64 + i * 512) * 16);
    }
  };

  auto TILE = [&](int t, int A) {
    if (t < 15) {
      STAGE(t + 1, A ^ 1);
      asm volatile("s_waitcnt vmcnt(6)" ::: "memory");  // tile t landed; t+1 in flight
    } else {
      asm volatile("s_waitcnt vmcnt(0)" ::: "memory");
    }
    __builtin_amdgcn_s_barrier();  // buf A readable by all waves

    const unsigned short* Ka = &Klds[A][0];
    const unsigned short* Va = &Vlds[A][0];
    const float* Ea = &Elds[A][0];

    // QK^T: ak fragments shared across both f
    f32x4 st[2][2];
#pragma unroll
    for (int f = 0; f < 2; ++f)
#pragma unroll
      for (int ct = 0; ct < 2; ++ct) st[f][ct] = (f32x4){0.f, 0.f, 0.f, 0.f};
#pragma unroll
    for (int kst = 0; kst < 4; ++kst) {
      bf16x8 ak[2];
#pragma unroll
      for (int ct = 0; ct < 2; ++ct) {
        const int r = ct * 16 + m;
        const int ph = (kst * 4 + g) ^ m;
        ak[ct] = *reinterpret_cast<const bf16x8*>(&Ka[r * 128 + ph * 8]);
      }
#pragma unroll
      for (int f = 0; f < 2; ++f)
#pragma unroll
        for (int ct = 0; ct < 2; ++ct)
          st[f][ct] = __builtin_amdgcn_mfma_f32_16x16x32_bf16(ak[ct], bq[f][kst],
                                                              st[f][ct], 0, 0, 0);
    }

    // gate with LDS-staged edge; pack P[q=m][32 keys] per (wave, f)
#pragma unroll
    for (int f = 0; f < 2; ++f)
#pragma unroll
      for (int ct = 0; ct < 2; ++ct) {
        const int ro = f * 128 + w * 16 + m;
        const int pe = (ct * 4 + g) ^ (m & 7);
        f32x4 ev = *reinterpret_cast<const f32x4*>(&Ea[ro * 32 + pe * 4]);
        u16x4 pv;
#pragma unroll
        for (int r = 0; r < 4; ++r) pv[r] = f2bf(ev[r] * st[f][ct][r]);
        const int ls = ct * 2 + (g >> 1);
        const int ps = ls ^ (m >> 2);
        *reinterpret_cast<u16x4*>(&p_lds[w][f][m][ps * 8 + (g & 1) * 4]) = pv;
      }

    // PV: bv fragments shared across both f (single K=32 step)
    {
      bf16x8 bv[8];
#pragma unroll
      for (int ct2 = 0; ct2 < 8; ++ct2) {
        const int c2 = ct2 * 16 + m;          // feature
        const int fr = c2 >> 2;               // V row (feature quad)
        const int lg = (c2 & 3) * 4 + g;      // fsub*4 + keygroup
        const int ph = lg ^ (fr & 15);
        bv[ct2] = *reinterpret_cast<const bf16x8*>(&Va[fr * 128 + ph * 8]);
      }
      const int psa = g ^ (m >> 2);
#pragma unroll
      for (int f = 0; f < 2; ++f) {
        bf16x8 ap = *reinterpret_cast<const bf16x8*>(&p_lds[w][f][m][psa * 8]);
#pragma unroll
        for (int ct2 = 0; ct2 < 8; ++ct2)
          acc_o[f][ct2] = __builtin_amdgcn_mfma_f32_16x16x32_bf16(
              ap, bv[ct2], acc_o[f][ct2], 0, 0, 0);
      }
    }

    // protect buffer A: next iteration stages tile t+2 into it
    __builtin_amdgcn_s_barrier();
  };

  STAGE(0, 0);
#pragma unroll 1
  for (int t2 = 0; t2 < 8; ++t2) {
    TILE(2 * t2, 0);
    TILE(2 * t2 + 1, 1);
  }

  // linear partial layout [kh][b*NN+row][ND] (R7-verified; no write-amp)
  float* pb = part + (size_t)kh * (NB * NN * ND);
#pragma unroll
  for (int f = 0; f < 2; ++f) {
    float* pf = pb + ((size_t)b * NN + q0 + f * 128) * ND;
#pragma unroll
    for (int ct2 = 0; ct2 < 8; ++ct2)
#pragma unroll
      for (int r = 0; r < 4; ++r)
        pf[(size_t)(g * 4 + r) * ND + ct2 * 16 + m] = acc_o[f][ct2][r];
  }
}

// merge 4 key-quarter partials + ReLU (R7-verified)
__global__ __launch_bounds__(256) void k_merge(const float* __restrict__ part,
                                               float* __restrict__ out, int n4) {
  int i = blockIdx.x * 256 + threadIdx.x;
  if (i >= n4) return;
  const f32x4* p = reinterpret_cast<const f32x4*>(part);
  const size_t s = (size_t)NB * NN * ND / 4;
  f32x4 v = p[i] + p[i + s] + p[i + 2 * s] + p[i + 3 * s];
#pragma unroll
  for (int j = 0; j < 4; ++j) v[j] = fmaxf(v[j], 0.f);
  reinterpret_cast<f32x4*>(out)[i] = v;
}

extern "C" void kernel_launch(void* const* d_in, const int* in_sizes, int n_in,
                              void* d_out, int out_size, void* d_ws, size_t ws_size,
                              hipStream_t stream) {
  const float* x = (const float*)d_in[0];
  const float* edge = (const float*)d_in[1];
  const float* W = (const float*)d_in[2];
  const float* bias = (const float*)d_in[3];
  float* out = (float*)d_out;

  unsigned short* hn = (unsigned short*)d_ws;                  // 4 MB
  unsigned short* hT = hn + (size_t)NB * NN * ND;              // 4 MB
  float* part = (float*)((char*)d_ws + 2 * (size_t)NB * NN * ND * 2);  // 32 MB

  k_linear<<<dim3((NB * NN) / 64), dim3(512), 0, stream>>>(x, W, bias, hn, hT);
  k_fused<<<dim3(256), dim3(512), 0, stream>>>(edge, hn, hT, part);
  const int n4 = out_size / 4;
  k_merge<<<dim3((n4 + 255) / 256), dim3(256), 0, stream>>>(part, out, n4);
}

// Round 12
// 52.704 us; speedup vs baseline: 2.0677x; 1.0959x over previous
//
#include <hip/hip_runtime.h>

#define NB 8
#define NN 2048
#define ND 128

typedef float f32x4 __attribute__((ext_vector_type(4)));
typedef __bf16 bf16x8 __attribute__((ext_vector_type(8)));
typedef unsigned short u16x4 __attribute__((ext_vector_type(4)));
typedef unsigned short u16x8 __attribute__((ext_vector_type(8)));

__device__ __forceinline__ unsigned short f2bf(float f) {
  unsigned u = __builtin_bit_cast(unsigned, f);
  u = (u + 0x7FFFu + ((u >> 16) & 1u)) >> 16;
  return (unsigned short)u;
}
__device__ __forceinline__ float bf2f(unsigned short s) {
  unsigned u = (unsigned)s << 16;
  return __builtin_bit_cast(float, u);
}

// async 16B global->LDS (DMA path); LDS dest = wave-uniform base + lane*16
__device__ __forceinline__ void stage16(const void* g, void* l) {
  __builtin_amdgcn_global_load_lds(
      (const __attribute__((address_space(1))) unsigned int*)g,
      (__attribute__((address_space(3))) unsigned int*)l, 16, 0, 0);
}

// K1: h = x @ W^T + b (fp32). hn = L2norm(h) bf16 [B*N, D]; hT = h bf16 [B, D, N].
__global__ __launch_bounds__(512, 2) void k_linear(
    const float* __restrict__ x, const float* __restrict__ W,
    const float* __restrict__ bias,
    unsigned short* __restrict__ hn, unsigned short* __restrict__ hT) {
  __shared__ __align__(16) float xs[128][68];
  __shared__ __align__(16) float wt[128][128];
  const int tid = threadIdx.x;
  const int rbase = blockIdx.x * 64;
  const int b = rbase >> 11;
  const int nb = rbase & (NN - 1);

#pragma unroll
  for (int j = 0; j < 4; ++j) {
    int f = tid + j * 512;
    int row = f >> 5;
    int kc = (f & 31) << 2;
    f32x4 v = *reinterpret_cast<const f32x4*>(&x[(size_t)(rbase + row) * ND + kc]);
#pragma unroll
    for (int i2 = 0; i2 < 4; ++i2) {
      int k = kc + i2;
      xs[k][row ^ (k & 28)] = v[i2];
    }
  }
#pragma unroll
  for (int j = 0; j < 8; ++j) {
    int f = tid + j * 512;
    int o = f >> 5;
    int i0 = (f & 31) << 2;
    f32x4 v = *reinterpret_cast<const f32x4*>(&W[(size_t)o * ND + i0]);
#pragma unroll
    for (int i2 = 0; i2 < 4; ++i2) {
      int k = i0 + i2;
      wt[k][o ^ (k & 28)] = v[i2];
    }
  }
  __syncthreads();

  const int tc = tid & 31;
  const int tr = tid >> 5;

  float acc[4][4];
#pragma unroll
  for (int r = 0; r < 4; ++r)
#pragma unroll
    for (int c = 0; c < 4; ++c) acc[r][c] = 0.f;

#pragma unroll 4
  for (int k = 0; k < 128; ++k) {
    const int sw = k & 28;
    f32x4 xv = *reinterpret_cast<const f32x4*>(&xs[k][(tr * 4) ^ sw]);
    f32x4 wv = *reinterpret_cast<const f32x4*>(&wt[k][(tc * 4) ^ sw]);
#pragma unroll
    for (int r = 0; r < 4; ++r)
#pragma unroll
      for (int c = 0; c < 4; ++c) acc[r][c] += xv[r] * wv[c];
  }

  f32x4 bv = *reinterpret_cast<const f32x4*>(&bias[tc * 4]);
#pragma unroll
  for (int r = 0; r < 4; ++r)
#pragma unroll
    for (int c = 0; c < 4; ++c) acc[r][c] += bv[c];

  float inv[4];
#pragma unroll
  for (int r = 0; r < 4; ++r) {
    float s = acc[r][0] * acc[r][0] + acc[r][1] * acc[r][1] +
              acc[r][2] * acc[r][2] + acc[r][3] * acc[r][3];
#pragma unroll
    for (int d = 1; d < 32; d <<= 1) s += __shfl_xor(s, d, 32);
    inv[r] = 1.f / fmaxf(sqrtf(s), 1e-12f);
  }

#pragma unroll
  for (int r = 0; r < 4; ++r) {
    u16x4 hv;
#pragma unroll
    for (int c = 0; c < 4; ++c) hv[c] = f2bf(acc[r][c] * inv[r]);
    *reinterpret_cast<u16x4*>(&hn[(size_t)(rbase + tr * 4 + r) * ND + tc * 4]) = hv;
  }
#pragma unroll
  for (int c = 0; c < 4; ++c) {
    u16x4 tv;
#pragma unroll
    for (int r = 0; r < 4; ++r) tv[r] = f2bf(acc[r][c]);
    *reinterpret_cast<u16x4*>(
        &hT[((size_t)b * ND + tc * 4 + c) * NN + nb + tr * 4]) = tv;
  }
}

// K2: part[kh] = (edge * (hn hn^T)) @ h over a 512-key slice, 128 q-rows/block.
// 512 blocks = (b = bid&7 [XCD], qt 0..15, kh 0..3), 8 waves x 16 q-rows,
// 16 tiles of 32 keys; K/V/E all DMA-staged (involutive XOR swizzles), dbuf,
// counted vmcnt(4) + two raw barriers. 72 KB LDS -> 2 blocks/CU (16 waves).
// Partials stored as bf16 (halves the partial HBM round-trip).
__global__ __launch_bounds__(512, 4) void k_fused(
    const float* __restrict__ edge,
    const unsigned short* __restrict__ hn,
    const unsigned short* __restrict__ hT,
    unsigned short* __restrict__ part) {
  __shared__ __align__(16) float Elds[2][128 * 32];            // 2 x 16 KB
  __shared__ __align__(16) unsigned short Klds[2][32 * 128];   // 2 x 8 KB
  __shared__ __align__(16) unsigned short Vlds[2][32 * 128];   // 2 x 8 KB
  __shared__ __align__(16) unsigned short p_lds[8][16][32];    // 8 KB

  const int tid = threadIdx.x;
  const int w = tid >> 6;
  const int l = tid & 63;
  const int m = l & 15;
  const int g = l >> 4;

  const int bid = blockIdx.x;
  const int b = bid & 7;           // XCD-batch affinity
  const int qt = (bid >> 3) & 15;  // 128-row q tile
  const int kh = bid >> 7;         // 0..3 key quarter

  const int q00 = qt * 128;
  const int q0 = q00 + w * 16;
  const unsigned short* hnb = hn + (size_t)b * NN * ND;
  const unsigned short* hTb = hT + (size_t)b * ND * NN;
  const float* eb = edge + (size_t)b * NN * NN;

  // Q fragments
  bf16x8 bq[4];
  {
    const unsigned short* qp = hnb + (size_t)(q0 + m) * ND + g * 8;
#pragma unroll
    for (int kst = 0; kst < 4; ++kst)
      bq[kst] = *reinterpret_cast<const bf16x8*>(qp + kst * 32);
  }

  f32x4 acc_o[8];
#pragma unroll
  for (int i = 0; i < 8; ++i) acc_o[i] = (f32x4){0.f, 0.f, 0.f, 0.f};

  // stage one 32-key tile: 4 stage16 per thread (K 1, V 1, E 2)
  auto STAGE = [&](int kt, int buf) {
    const int kb = kh * 512 + kt * 32;
    {  // K: 32 rows x 16 slots; src slot = c ^ (r&15)
      int r = tid >> 4, c = tid & 15;
      int lg = c ^ (r & 15);
      stage16(hnb + (size_t)(kb + r) * ND + lg * 8,
              (char*)&Klds[buf][0] + (size_t)(w * 64) * 16);
    }
    {  // V: 32 feature-quad rows x 16 slots; ft = fr*4 + (lg>>2), keys (lg&3)*8
      int fr = tid >> 4, c = tid & 15;
      int lg = c ^ (fr & 15);
      int ft = fr * 4 + (lg >> 2);
      stage16(hTb + (size_t)ft * NN + kb + (lg & 3) * 8,
              (char*)&Vlds[buf][0] + (size_t)(w * 64) * 16);
    }
#pragma unroll
    for (int i = 0; i < 2; ++i) {  // E: 128 rows x 8 slots; src slot = c ^ (r&7)
      int ch = tid + i * 512;
      int r2 = ch >> 3, c = ch & 7;
      int lg = c ^ (r2 & 7);
      stage16(eb + (size_t)(q00 + r2) * NN + kb + lg * 4,
              (char*)&Elds[buf][0] + (size_t)(w * 64 + i * 512) * 16);
    }
  };

  auto TILE = [&](int t, int A) {
    if (t < 15) {
      STAGE(t + 1, A ^ 1);
      asm volatile("s_waitcnt vmcnt(4)" ::: "memory");  // tile t landed; t+1 in flight
    } else {
      asm volatile("s_waitcnt vmcnt(0)" ::: "memory");
    }
    __builtin_amdgcn_s_barrier();  // buf A readable by all waves

    const unsigned short* Ka = &Klds[A][0];
    const unsigned short* Va = &Vlds[A][0];
    const float* Ea = &Elds[A][0];

    // QK^T (32 keys)
    f32x4 st[2];
#pragma unroll
    for (int ct = 0; ct < 2; ++ct) st[ct] = (f32x4){0.f, 0.f, 0.f, 0.f};
#pragma unroll
    for (int kst = 0; kst < 4; ++kst) {
      bf16x8 ak[2];
#pragma unroll
      for (int ct = 0; ct < 2; ++ct) {
        const int r = ct * 16 + m;
        const int ph = (kst * 4 + g) ^ m;
        ak[ct] = *reinterpret_cast<const bf16x8*>(&Ka[r * 128 + ph * 8]);
      }
#pragma unroll
      for (int ct = 0; ct < 2; ++ct)
        st[ct] = __builtin_amdgcn_mfma_f32_16x16x32_bf16(ak[ct], bq[kst], st[ct], 0, 0, 0);
    }

    // gate with LDS-staged edge; pack P[q=m][32 keys]
#pragma unroll
    for (int ct = 0; ct < 2; ++ct) {
      const int ro = w * 16 + m;
      const int pe = (ct * 4 + g) ^ (m & 7);
      f32x4 ev = *reinterpret_cast<const f32x4*>(&Ea[ro * 32 + pe * 4]);
      u16x4 pv;
#pragma unroll
      for (int r = 0; r < 4; ++r) pv[r] = f2bf(ev[r] * st[ct][r]);
      const int ls = ct * 2 + (g >> 1);
      const int ps = ls ^ (m >> 2);
      *reinterpret_cast<u16x4*>(&p_lds[w][m][ps * 8 + (g & 1) * 4]) = pv;
    }

    // PV (single K=32 step)
    {
      bf16x8 bv[8];
#pragma unroll
      for (int ct2 = 0; ct2 < 8; ++ct2) {
        const int c2 = ct2 * 16 + m;          // feature
        const int fr = c2 >> 2;               // V row (feature quad)
        const int lg = (c2 & 3) * 4 + g;
        const int ph = lg ^ (fr & 15);
        bv[ct2] = *reinterpret_cast<const bf16x8*>(&Va[fr * 128 + ph * 8]);
      }
      const int psa = g ^ (m >> 2);
      bf16x8 ap = *reinterpret_cast<const bf16x8*>(&p_lds[w][m][psa * 8]);
#pragma unroll
      for (int ct2 = 0; ct2 < 8; ++ct2)
        acc_o[ct2] = __builtin_amdgcn_mfma_f32_16x16x32_bf16(ap, bv[ct2], acc_o[ct2], 0, 0, 0);
    }

    // protect buffer A: next iteration stages tile t+2 into it
    __builtin_amdgcn_s_barrier();
  };

  STAGE(0, 0);
#pragma unroll 1
  for (int t2 = 0; t2 < 8; ++t2) {
    TILE(2 * t2, 0);
    TILE(2 * t2 + 1, 1);
  }

  // bf16 partial store, linear layout [kh][b*NN+row][ND]
  unsigned short* pf =
      part + (size_t)kh * (NB * NN * ND) + ((size_t)b * NN + q0) * ND;
#pragma unroll
  for (int ct2 = 0; ct2 < 8; ++ct2)
#pragma unroll
    for (int r = 0; r < 4; ++r)
      pf[(size_t)(g * 4 + r) * ND + ct2 * 16 + m] = f2bf(acc_o[ct2][r]);
}

// merge 4 bf16 key-quarter partials + ReLU -> fp32 out
__global__ __launch_bounds__(256) void k_merge(const unsigned short* __restrict__ part,
                                               float* __restrict__ out, int n8) {
  int i = blockIdx.x * 256 + threadIdx.x;
  if (i >= n8) return;
  const size_t s = (size_t)NB * NN * ND;
  float acc[8];
#pragma unroll
  for (int j = 0; j < 8; ++j) acc[j] = 0.f;
#pragma unroll
  for (int q = 0; q < 4; ++q) {
    u16x8 v = *reinterpret_cast<const u16x8*>(&part[q * s + (size_t)i * 8]);
#pragma unroll
    for (int j = 0; j < 8; ++j) acc[j] += bf2f(v[j]);
  }
  f32x4 o0, o1;
#pragma unroll
  for (int j = 0; j < 4; ++j) {
    o0[j] = fmaxf(acc[j], 0.f);
    o1[j] = fmaxf(acc[4 + j], 0.f);
  }
  *reinterpret_cast<f32x4*>(&out[(size_t)i * 8]) = o0;
  *reinterpret_cast<f32x4*>(&out[(size_t)i * 8 + 4]) = o1;
}

extern "C" void kernel_launch(void* const* d_in, const int* in_sizes, int n_in,
                              void* d_out, int out_size, void* d_ws, size_t ws_size,
                              hipStream_t stream) {
  const float* x = (const float*)d_in[0];
  const float* edge = (const float*)d_in[1];
  const float* W = (const float*)d_in[2];
  const float* bias = (const float*)d_in[3];
  float* out = (float*)d_out;

  unsigned short* hn = (unsigned short*)d_ws;                  // 4 MB
  unsigned short* hT = hn + (size_t)NB * NN * ND;              // 4 MB
  unsigned short* part = hT + (size_t)NB * NN * ND;            // 16 MB (bf16 x4)

  k_linear<<<dim3((NB * NN) / 64), dim3(512), 0, stream>>>(x, W, bias, hn, hT);
  k_fused<<<dim3(512), dim3(512), 0, stream>>>(edge, hn, hT, part);
  const int n8 = out_size / 8;
  k_merge<<<dim3((n8 + 255) / 256), dim3(256), 0, stream>>>(part, out, n8);
}